// Round 1
// baseline (233.914 us; speedup 1.0000x reference)
//
#include <hip/hip_runtime.h>

#define S_LEN 1024
#define DH 64
#define QB 64      // q rows per workgroup
#define KT 64      // k rows per tile
#define NKT 16     // S_LEN / KT
#define LDP 72     // padded LDS row length (bf16 elems): 144B stride -> 2-way-bank only

typedef __attribute__((ext_vector_type(8))) short bf16x8;
typedef __attribute__((ext_vector_type(4))) float f32x4;

__device__ __forceinline__ unsigned short f2bf(float f) {
  unsigned u = __float_as_uint(f);
  u = u + 0x7FFFu + ((u >> 16) & 1u);   // round-to-nearest-even
  return (unsigned short)(u >> 16);
}

__global__ __launch_bounds__(256)
void sdpa_kernel(const float* __restrict__ qg, const float* __restrict__ kg,
                 const float* __restrict__ vg, const int* __restrict__ maskg,
                 float* __restrict__ outg, float* __restrict__ attng)
{
  __shared__ unsigned short Qs[QB][LDP];
  __shared__ unsigned short Ks[KT][LDP];
  __shared__ unsigned short Vt[DH][LDP];      // V transposed: [d][k]
  __shared__ unsigned short Ps[4][16][LDP];   // per-wave P tile (16 q x 64 k)

  const int tid  = threadIdx.x;
  const int wid  = tid >> 6;
  const int lane = tid & 63;
  const int lrow = lane & 15;   // MFMA fragment row / C col
  const int lhi  = lane >> 4;   // MFMA k-group / C row group

  const int blk = blockIdx.x;
  const int qbi = blk & 15;     // q-block index
  const int bh  = blk >> 4;     // fused batch*head
  const int b   = bh >> 4;

  const size_t qkv_off = (size_t)bh * (S_LEN * DH);
  const float* qb_ptr = qg + qkv_off + (size_t)qbi * QB * DH;
  const float* kb_ptr = kg + qkv_off;
  const float* vb_ptr = vg + qkv_off;
  const int*   mb_ptr = maskg + (size_t)b * (S_LEN * S_LEN);
  const int q0 = qbi * QB;

  // ---- stage Q (64x64 f32 -> bf16, coalesced float4 reads) ----
  #pragma unroll
  for (int i = 0; i < 4; ++i) {
    int idx = tid + 256 * i;
    int row = idx >> 4;
    int c4  = (idx & 15) << 2;
    float4 t = *(const float4*)(qb_ptr + row * DH + c4);
    ushort4 pk;
    pk.x = f2bf(t.x); pk.y = f2bf(t.y); pk.z = f2bf(t.z); pk.w = f2bf(t.w);
    *(ushort4*)&Qs[row][c4] = pk;
  }
  __syncthreads();

  // wave-resident Q fragments (A-frag: row = lane&15, k = (lane>>4)*8 + i)
  const bf16x8 qf0 = *(const bf16x8*)&Qs[wid * 16 + lrow][lhi * 8];
  const bf16x8 qf1 = *(const bf16x8*)&Qs[wid * 16 + lrow][32 + lhi * 8];

  const int qrow_l = wid * 16 + lhi * 4;   // this lane's C-row base (local)

  // ================= pass 1: row sums of exp(masked scores) =================
  float rs[4] = {0.f, 0.f, 0.f, 0.f};

  for (int kt = 0; kt < NKT; ++kt) {
    __syncthreads();
    #pragma unroll
    for (int i = 0; i < 4; ++i) {
      int idx = tid + 256 * i;
      int row = idx >> 4;
      int c4  = (idx & 15) << 2;
      float4 t = *(const float4*)(kb_ptr + (size_t)(kt * KT + row) * DH + c4);
      ushort4 pk;
      pk.x = f2bf(t.x); pk.y = f2bf(t.y); pk.z = f2bf(t.z); pk.w = f2bf(t.w);
      *(ushort4*)&Ks[row][c4] = pk;
    }
    __syncthreads();

    #pragma unroll
    for (int nt = 0; nt < 4; ++nt) {
      bf16x8 kf0 = *(const bf16x8*)&Ks[nt * 16 + lrow][lhi * 8];
      bf16x8 kf1 = *(const bf16x8*)&Ks[nt * 16 + lrow][32 + lhi * 8];
      f32x4 acc = {0.f, 0.f, 0.f, 0.f};
      acc = __builtin_amdgcn_mfma_f32_16x16x32_bf16(qf0, kf0, acc, 0, 0, 0);
      acc = __builtin_amdgcn_mfma_f32_16x16x32_bf16(qf1, kf1, acc, 0, 0, 0);
      const int kcol = kt * KT + nt * 16 + lrow;
      const int* mp = mb_ptr + (size_t)(q0 + qrow_l) * S_LEN + kcol;
      #pragma unroll
      for (int r = 0; r < 4; ++r) {
        int m = mp[(size_t)r * S_LEN];
        float p = (m != 0) ? __expf(acc[r] * 0.125f) : 0.f;
        rs[r] += p;
      }
    }
  }

  // reduce partial row sums across the 16 lanes that share each q-row
  #pragma unroll
  for (int r = 0; r < 4; ++r) {
    float v = rs[r];
    v += __shfl_xor(v, 1);
    v += __shfl_xor(v, 2);
    v += __shfl_xor(v, 4);
    v += __shfl_xor(v, 8);
    rs[r] = v;
  }
  float inv[4];
  #pragma unroll
  for (int r = 0; r < 4; ++r) inv[r] = 1.0f / rs[r];

  // ================= pass 2: recompute, write attn, accumulate PV =================
  f32x4 oacc[4];
  #pragma unroll
  for (int dt = 0; dt < 4; ++dt) oacc[dt] = (f32x4){0.f, 0.f, 0.f, 0.f};

  float* attn_base = attng + (size_t)bh * (S_LEN * S_LEN);

  for (int kt = 0; kt < NKT; ++kt) {
    __syncthreads();
    // stage K tile (row-major)
    #pragma unroll
    for (int i = 0; i < 4; ++i) {
      int idx = tid + 256 * i;
      int row = idx >> 4;
      int c4  = (idx & 15) << 2;
      float4 t = *(const float4*)(kb_ptr + (size_t)(kt * KT + row) * DH + c4);
      ushort4 pk;
      pk.x = f2bf(t.x); pk.y = f2bf(t.y); pk.z = f2bf(t.z); pk.w = f2bf(t.w);
      *(ushort4*)&Ks[row][c4] = pk;
    }
    // stage V tile transposed: thread reads V[row][c4..c4+3], writes Vt[c4+j][row]
    // mapping row = idx&63 keeps LDS write conflicts to same-dword pairs
    #pragma unroll
    for (int i = 0; i < 4; ++i) {
      int idx = tid + 256 * i;
      int row = idx & 63;
      int c4  = (idx >> 6) << 2;
      float4 t = *(const float4*)(vb_ptr + (size_t)(kt * KT + row) * DH + c4);
      Vt[c4 + 0][row] = f2bf(t.x);
      Vt[c4 + 1][row] = f2bf(t.y);
      Vt[c4 + 2][row] = f2bf(t.z);
      Vt[c4 + 3][row] = f2bf(t.w);
    }
    __syncthreads();

    #pragma unroll
    for (int nt = 0; nt < 4; ++nt) {
      bf16x8 kf0 = *(const bf16x8*)&Ks[nt * 16 + lrow][lhi * 8];
      bf16x8 kf1 = *(const bf16x8*)&Ks[nt * 16 + lrow][32 + lhi * 8];
      f32x4 acc = {0.f, 0.f, 0.f, 0.f};
      acc = __builtin_amdgcn_mfma_f32_16x16x32_bf16(qf0, kf0, acc, 0, 0, 0);
      acc = __builtin_amdgcn_mfma_f32_16x16x32_bf16(qf1, kf1, acc, 0, 0, 0);
      const int kcol = kt * KT + nt * 16 + lrow;
      const int* mp = mb_ptr + (size_t)(q0 + qrow_l) * S_LEN + kcol;
      float* ap = attn_base + (size_t)(q0 + qrow_l) * S_LEN + kcol;
      #pragma unroll
      for (int r = 0; r < 4; ++r) {
        int m = mp[(size_t)r * S_LEN];
        float p = (m != 0) ? __expf(acc[r] * 0.125f) : 0.f;
        ap[(size_t)r * S_LEN] = p * inv[r];               // attn output (f32)
        Ps[wid][lhi * 4 + r][nt * 16 + lrow] = f2bf(p);   // P for PV (bf16)
      }
    }

    // PV: A-frag from per-wave Ps, B-frag from transposed Vt
    bf16x8 pf0 = *(const bf16x8*)&Ps[wid][lrow][lhi * 8];
    bf16x8 pf1 = *(const bf16x8*)&Ps[wid][lrow][32 + lhi * 8];
    #pragma unroll
    for (int dt = 0; dt < 4; ++dt) {
      bf16x8 vf0 = *(const bf16x8*)&Vt[dt * 16 + lrow][lhi * 8];
      bf16x8 vf1 = *(const bf16x8*)&Vt[dt * 16 + lrow][32 + lhi * 8];
      oacc[dt] = __builtin_amdgcn_mfma_f32_16x16x32_bf16(pf0, vf0, oacc[dt], 0, 0, 0);
      oacc[dt] = __builtin_amdgcn_mfma_f32_16x16x32_bf16(pf1, vf1, oacc[dt], 0, 0, 0);
    }
  }

  // ---- epilogue: normalized output ----
  #pragma unroll
  for (int dt = 0; dt < 4; ++dt) {
    #pragma unroll
    for (int r = 0; r < 4; ++r) {
      outg[qkv_off + (size_t)(q0 + qrow_l + r) * DH + dt * 16 + lrow] = oacc[dt][r] * inv[r];
    }
  }
}

extern "C" void kernel_launch(void* const* d_in, const int* in_sizes, int n_in,
                              void* d_out, int out_size, void* d_ws, size_t ws_size,
                              hipStream_t stream) {
  const float* q    = (const float*)d_in[0];
  const float* k    = (const float*)d_in[1];
  const float* v    = (const float*)d_in[2];
  const int*   mask = (const int*)d_in[3];
  float* out  = (float*)d_out;
  float* attn = out + (size_t)4 * 16 * 1024 * 64;   // output first, then attn
  sdpa_kernel<<<dim3(64 * 16), dim3(256), 0, stream>>>(q, k, v, mask, out, attn);
}